// Round 10
// baseline (165.973 us; speedup 1.0000x reference)
//
#include <hip/hip_runtime.h>

// StickyRNN: B=2048, T=1024, VOCAB=65, EMBED=6, HIDDEN=7
#define TV 65
#define NB 2048
#define NT 1024

typedef float f32x4 __attribute__((ext_vector_type(4)));

// workspace layout (in floats)
#define OFF_SP 0         // SP[cur*65+prev] = float2(Stc, Src)            (2*4225)
#define OFF_LP 8450      // LP[v*65+u]      = float2(Ltc, Lrc)            (2*4225)
#define OFF_S0 16900     // S0[v] = dot(embed[v], hidden_init[0:6])       (65)
#define OFF_R  17792     // r[b*T+t] reset gate per step                  (2M), 64B-aligned

// Fused table build: one block (identical to R5/R7/R8).
__global__ __launch_bounds__(256) void k_build(
    const float* __restrict__ embed, const float* __restrict__ ct,
    const float* __restrict__ rt, const float* __restrict__ hinit,
    const float* __restrict__ outw, float* __restrict__ ws) {
  __shared__ float tc_s[TV][6];
  __shared__ float rc_s[TV][6];
  int v = threadIdx.x;
  if (v < TV) {
    float e[6];
#pragma unroll
    for (int k = 0; k < 6; k++) e[k] = embed[v * 6 + k];
#pragma unroll
    for (int j = 0; j < 6; j++) {
      float stc = 0.f, src = 0.f;
#pragma unroll
      for (int k = 0; k < 6; k++) {
        stc += e[k] * ct[k * 6 + j];
        src += e[k] * rt[k * 6 + j];
      }
      tc_s[v][j] = stc;
      rc_s[v][j] = src;
    }
    float s0 = 0.f;
#pragma unroll
    for (int k = 0; k < 6; k++) s0 += e[k] * hinit[k];
    ws[OFF_S0 + v] = s0;
  }
  __syncthreads();
  for (int idx = threadIdx.x; idx < 2 * 4225; idx += 256) {
    int tbl = idx / 4225;
    int e2 = idx - tbl * 4225;
    int a = e2 / 65;
    int b = e2 - a * 65;
    if (tbl == 0) {
      float stc = 0.f, src = 0.f;
#pragma unroll
      for (int k = 0; k < 6; k++) {
        stc += embed[a * 6 + k] * tc_s[b][k];
        src += embed[a * 6 + k] * rc_s[b][k];
      }
      ((float2*)(ws + OFF_SP))[e2] = make_float2(stc, src);
    } else {
      float ltc = 0.f, lrc = 0.f;
#pragma unroll
      for (int k = 0; k < 6; k++) {
        ltc += tc_s[a][k] * outw[k * 65 + b];
        lrc += rc_s[a][k] * outw[k * 65 + b];
      }
      ((float2*)(ws + OFF_LP))[e2] = make_float2(ltc, lrc);
    }
  }
}

// Speculative chunk-parallel recurrence (bitwise-verified R2 vs R3).
__global__ __launch_bounds__(256) void k_rnn_spec(
    const int* __restrict__ x, float* __restrict__ ws,
    const float* __restrict__ thr, const float* __restrict__ temp,
    const float* __restrict__ hinit) {
  __shared__ float2 sSP[4225];
  const float2* __restrict__ gSP = (const float2*)(ws + OFF_SP);
  for (int i = threadIdx.x; i < 4225; i += 256) sSP[i] = gSP[i];
  __syncthreads();

  const int tid = blockIdx.x * 256 + threadIdx.x;  // 0..65535
  const int c = tid >> 11;                         // chunk 0..31 (block-uniform)
  const int row = tid & 2047;
  const int t0 = c * 32;
  int s0 = t0 - 96;
  if (s0 < 0) s0 = 0;
  const bool exact = (s0 == 0);
  const int NG = (t0 + 32 - s0) >> 2;  // 8/16/24/32 groups of 4 steps

  const float t0v = thr[0];
  const float thr2 = t0v * t0v;
  const float invtemp = 1.0f / temp[0];
  const int* xp = x + row * NT;
  float* rbase = ws + OFF_R + row * NT;

  int4 xa = *(const int4*)(xp + s0);
  int4 xb = *(const int4*)(xp + s0 + 4);
  int4 xc = *(const int4*)(xp + s0 + 8);
  int4 xd = *(const int4*)(xp + s0 + 12);

  float pa, r_prev, omr_prev;
  float2 sp0;
  if (exact) {
    float s0v = ws[OFF_S0 + xa.x];
    sp0 = make_float2(s0v, s0v);  // 0.5*s+0.5*s == s exactly
    pa = hinit[6];
    r_prev = 0.5f;
    omr_prev = 0.5f;
  } else {
    int vm1 = xp[s0 - 1];
    sp0 = sSP[xa.x * 65 + vm1];
    pa = 0.0f;
    r_prev = 1.0f;
    omr_prev = 0.0f;
  }
  float2 sp1 = sSP[xa.y * 65 + xa.x];
  float2 sp2 = sSP[xa.z * 65 + xa.y];
  float2 sp3 = sSP[xa.w * 65 + xa.z];

#define STEP(SP, ROUT)                               \
  {                                                  \
    float sim = r_prev * (SP).y + omr_prev * (SP).x; \
    float prod = (1.0f + pa) * sim;                  \
    float aa = fmaxf(prod, 0.0f);                    \
    float add = aa - pa;                             \
    float na = pa + add;                             \
    float p = __expf((thr2 - na) * invtemp);         \
    float r = __builtin_amdgcn_rcpf(1.0f + p);       \
    float omr = 1.0f - r;                            \
    pa = omr * na;                                   \
    r_prev = r;                                      \
    omr_prev = omr;                                  \
    ROUT = r;                                        \
  }

  for (int g = 0; g < NG; ++g) {
    int offn = s0 + 4 * (g + 4);
    if (offn > NT - 4) offn = s0;
    int4 xe = *(const int4*)(xp + offn);
    float2 n0 = sSP[xb.x * 65 + xa.w];
    float2 n1 = sSP[xb.y * 65 + xb.x];
    float2 n2 = sSP[xb.z * 65 + xb.y];
    float2 n3 = sSP[xb.w * 65 + xb.z];

    float4 rq;
    STEP(sp0, rq.x);
    STEP(sp1, rq.y);
    STEP(sp2, rq.z);
    STEP(sp3, rq.w);
    int st = s0 + 4 * g;
    if (st >= t0) *(float4*)(rbase + st) = rq;  // block-uniform branch

    sp0 = n0; sp1 = n1; sp2 = n2; sp3 = n3;
    xa = xb; xb = xc; xc = xd; xd = xe;
  }
#undef STEP
}

// logits[n*65+v] = r_n * Lrc[x_n][v] + (1-r_n) * Ltc[x_n][v]
// R8 config (2048 blocks, branchless, LDS-LP unswizzled) with ONE change:
// plain cached dwordx4 store instead of nontemporal. The harness fills
// prove cached streaming stores sustain 6.6 TB/s on this exact buffer;
// NT was never A/B'd single-variable and may map to an uncached MTYPE
// (per-16B transactions, no write-combining).
#define NF4 34078720u   // 2048*1024*65/4
#define PSTRIDE 524288u // 2048*256
__global__ __launch_bounds__(256) void k_proj(
    const int* __restrict__ x, const float* __restrict__ ws,
    float* __restrict__ out) {
  __shared__ float2 sLP[4225];
  const float2* __restrict__ gLP = (const float2*)(ws + OFF_LP);
  for (int i = threadIdx.x; i < 4225; i += 256) sLP[i] = gLP[i];
  __syncthreads();

  unsigned gid = blockIdx.x * 256u + threadIdx.x;
  for (unsigned i4 = gid; i4 < NF4; i4 += PSTRIDE) {
    unsigned base = i4 * 4u;
    unsigned n = base / 65u;
    unsigned v = base - n * 65u;  // 0..64
    unsigned n1 = n + 1u;
    if (n1 > 2097151u) n1 = 2097151u;  // last float4 has v==61: never wraps
    int xv = x[n];
    int xv2 = x[n1];
    float r = ws[OFF_R + n];
    float r2 = ws[OFF_R + n1];
    float omr = 1.0f - r;
    float omr2 = 1.0f - r2;
    unsigned offA = (unsigned)xv * 65u + v;         // element j (no wrap): offA + j
    unsigned offB = (unsigned)xv2 * 65u + v - 65u;  // element j (wrap):    offB + j
    f32x4 o;
#pragma unroll
    for (int j = 0; j < 4; ++j) {
      bool wrap = (v + (unsigned)j) >= 65u;
      unsigned off = (wrap ? offB : offA) + (unsigned)j;
      float2 p = sLP[off];
      float rr = wrap ? r2 : r;
      float oo = wrap ? omr2 : omr;
      o[j] = rr * p.y + oo * p.x;
    }
    *(f32x4*)(out + base) = o;
  }
}

extern "C" void kernel_launch(void* const* d_in, const int* in_sizes, int n_in,
                              void* d_out, int out_size, void* d_ws, size_t ws_size,
                              hipStream_t stream) {
  const int* x = (const int*)d_in[0];
  const float* embed = (const float*)d_in[1];
  const float* hinit = (const float*)d_in[2];
  const float* thr = (const float*)d_in[3];
  const float* temp = (const float*)d_in[4];
  const float* ct = (const float*)d_in[5];
  const float* rt = (const float*)d_in[6];
  const float* outw = (const float*)d_in[7];
  float* ws = (float*)d_ws;
  float* out = (float*)d_out;

  hipLaunchKernelGGL(k_build, dim3(1), dim3(256), 0, stream, embed, ct, rt, hinit, outw, ws);
  // 2048 rows x 32 chunks = 65536 threads = 256 blocks
  hipLaunchKernelGGL(k_rnn_spec, dim3(256), dim3(256), 0, stream, x, ws, thr, temp, hinit);
  hipLaunchKernelGGL(k_proj, dim3(2048), dim3(256), 0, stream, x, ws, out);
}

// Round 11
// 141.277 us; speedup vs baseline: 1.1748x; 1.1748x over previous
//
#include <hip/hip_runtime.h>

// StickyRNN: B=2048, T=1024, VOCAB=65, EMBED=6, HIDDEN=7
#define TV 65
#define NB 2048
#define NT 1024

typedef float f32x4 __attribute__((ext_vector_type(4)));

// workspace layout (in floats)
#define OFF_SP 0         // SP[cur*65+prev] = float2(Stc, Src)            (2*4225)
#define OFF_LP 8450      // LP[v*65+u]      = float2(Ltc, Lrc)            (2*4225)
#define OFF_S0 16900     // S0[v] = dot(embed[v], hidden_init[0:6])       (65)

// Fused table build: one block (identical to R5..R10).
__global__ __launch_bounds__(256) void k_build(
    const float* __restrict__ embed, const float* __restrict__ ct,
    const float* __restrict__ rt, const float* __restrict__ hinit,
    const float* __restrict__ outw, float* __restrict__ ws) {
  __shared__ float tc_s[TV][6];
  __shared__ float rc_s[TV][6];
  int v = threadIdx.x;
  if (v < TV) {
    float e[6];
#pragma unroll
    for (int k = 0; k < 6; k++) e[k] = embed[v * 6 + k];
#pragma unroll
    for (int j = 0; j < 6; j++) {
      float stc = 0.f, src = 0.f;
#pragma unroll
      for (int k = 0; k < 6; k++) {
        stc += e[k] * ct[k * 6 + j];
        src += e[k] * rt[k * 6 + j];
      }
      tc_s[v][j] = stc;
      rc_s[v][j] = src;
    }
    float s0 = 0.f;
#pragma unroll
    for (int k = 0; k < 6; k++) s0 += e[k] * hinit[k];
    ws[OFF_S0 + v] = s0;
  }
  __syncthreads();
  for (int idx = threadIdx.x; idx < 2 * 4225; idx += 256) {
    int tbl = idx / 4225;
    int e2 = idx - tbl * 4225;
    int a = e2 / 65;
    int b = e2 - a * 65;
    if (tbl == 0) {
      float stc = 0.f, src = 0.f;
#pragma unroll
      for (int k = 0; k < 6; k++) {
        stc += embed[a * 6 + k] * tc_s[b][k];
        src += embed[a * 6 + k] * rc_s[b][k];
      }
      ((float2*)(ws + OFF_SP))[e2] = make_float2(stc, src);
    } else {
      float ltc = 0.f, lrc = 0.f;
#pragma unroll
      for (int k = 0; k < 6; k++) {
        ltc += tc_s[a][k] * outw[k * 65 + b];
        lrc += rc_s[a][k] * outw[k * 65 + b];
      }
      ((float2*)(ws + OFF_LP))[e2] = make_float2(ltc, lrc);
    }
  }
}

// Fused recurrence + projection. Block b owns rows [4b, 4b+4).
// Phase A: stage x (uchar) + SP into LDS; threads 0..127 run the
//   speculative chunk recurrence (bitwise-identical STEP/warmup to R8),
//   r written to LDS only — no global round-trip.
// Phase B: swap LDS table to LP; all 256 threads write the block's
//   contiguous 1.06 MB output segment. ZERO global reads in this loop
//   (x, r, LP all LDS) and sequential store addresses -> fill-shaped.
__global__ __launch_bounds__(256) void k_fused(
    const int* __restrict__ x, const float* __restrict__ ws,
    const float* __restrict__ thr, const float* __restrict__ temp,
    const float* __restrict__ hinit, float* __restrict__ out) {
  __shared__ float2 sTab[4225];            // SP during phase A, LP during B
  __shared__ float r_s[4 * 1024];
  __shared__ unsigned char x_s[4 * 1024];

  const int b = blockIdx.x;
  const int t = threadIdx.x;

  // stage x rows (coalesced int4 -> uchar) and SP table
  const int* xg = x + b * 4096;
  for (int i = t; i < 1024; i += 256) {
    int4 xv4 = ((const int4*)xg)[i];
    ((uchar4*)x_s)[i] = make_uchar4((unsigned char)xv4.x, (unsigned char)xv4.y,
                                    (unsigned char)xv4.z, (unsigned char)xv4.w);
  }
  const float2* __restrict__ gSP = (const float2*)(ws + OFF_SP);
  for (int i = t; i < 4225; i += 256) sTab[i] = gSP[i];
  __syncthreads();

  // ---------- Phase A: recurrence (threads 0..127) ----------
  if (t < 128) {
    const int chunk = t & 31;
    const int row_loc = t >> 5;  // 0..3
    const int t0 = chunk * 32;
    int s0 = t0 - 96;
    if (s0 < 0) s0 = 0;
    const bool exact = (s0 == 0);
    const int NG = (t0 + 32 - s0) >> 2;

    const float t0v = thr[0];
    const float thr2 = t0v * t0v;
    const float invtemp = 1.0f / temp[0];
    const unsigned char* xp = x_s + row_loc * 1024;
    float* rp = r_s + row_loc * 1024;

    unsigned tw = *(const unsigned*)(xp + s0);
    unsigned a0 = tw & 255u, a1 = (tw >> 8) & 255u;
    unsigned a2 = (tw >> 16) & 255u, a3 = tw >> 24;

    float pa, r_prev, omr_prev;
    float2 sp0;
    if (exact) {
      float s0v = ws[OFF_S0 + a0];
      sp0 = make_float2(s0v, s0v);  // 0.5*s+0.5*s == s exactly
      pa = hinit[6];
      r_prev = 0.5f;
      omr_prev = 0.5f;
    } else {
      unsigned vm1 = xp[s0 - 1];
      sp0 = sTab[a0 * 65 + vm1];
      pa = 0.0f;
      r_prev = 1.0f;
      omr_prev = 0.0f;
    }
    float2 sp1 = sTab[a1 * 65 + a0];
    float2 sp2 = sTab[a2 * 65 + a1];
    float2 sp3 = sTab[a3 * 65 + a2];
    unsigned last = a3;

#define STEP(SP, ROUT)                               \
  {                                                  \
    float sim = r_prev * (SP).y + omr_prev * (SP).x; \
    float prod = (1.0f + pa) * sim;                  \
    float aa = fmaxf(prod, 0.0f);                    \
    float add = aa - pa;                             \
    float na = pa + add;                             \
    float p = __expf((thr2 - na) * invtemp);         \
    float r = __builtin_amdgcn_rcpf(1.0f + p);       \
    float omr = 1.0f - r;                            \
    pa = omr * na;                                   \
    r_prev = r;                                      \
    omr_prev = omr;                                  \
    ROUT = r;                                        \
  }

    for (int g = 0; g < NG; ++g) {
      // next-group tokens + table pairs (clamped on tail; values unused)
      int offn = s0 + 4 * (g + 1);
      if (offn > NT - 4) offn = s0;
      unsigned twn = *(const unsigned*)(xp + offn);
      unsigned b0 = twn & 255u, b1 = (twn >> 8) & 255u;
      unsigned b2 = (twn >> 16) & 255u, b3 = twn >> 24;
      float2 n0 = sTab[b0 * 65 + last];
      float2 n1v = sTab[b1 * 65 + b0];
      float2 n2 = sTab[b2 * 65 + b1];
      float2 n3 = sTab[b3 * 65 + b2];

      float4 rq;
      STEP(sp0, rq.x);
      STEP(sp1, rq.y);
      STEP(sp2, rq.z);
      STEP(sp3, rq.w);
      int st = s0 + 4 * g;
      if (st >= t0) *(float4*)(rp + st) = rq;

      sp0 = n0; sp1 = n1v; sp2 = n2; sp3 = n3;
      last = b3;
    }
#undef STEP
  }
  __syncthreads();

  // swap table: SP -> LP
  const float2* __restrict__ gLP = (const float2*)(ws + OFF_LP);
  for (int i = t; i < 4225; i += 256) sTab[i] = gLP[i];
  __syncthreads();

  // ---------- Phase B: projection (all threads) ----------
  // block segment: 4 rows x 1024 tok x 65 vocab = 266240 floats = 66560 f4
  float* ob = out + (size_t)b * 266240u;
  for (unsigned i4 = t; i4 < 66560u; i4 += 256u) {
    unsigned base = i4 * 4u;
    unsigned n = base / 65u;        // 0..4095 block-local token
    unsigned v = base - n * 65u;    // 0..64
    unsigned n1i = n + 1u;
    if (n1i > 4095u) n1i = 4095u;   // last f4 of segment has v==61: never wraps
    unsigned xv = x_s[n];
    unsigned xv2 = x_s[n1i];
    float r = r_s[n], r2 = r_s[n1i];
    float omr = 1.0f - r, omr2 = 1.0f - r2;
    unsigned offA = xv * 65u + v;          // element j (no wrap): offA + j
    unsigned offB = xv2 * 65u + v - 65u;   // element j (wrap):    offB + j
    f32x4 o;
#pragma unroll
    for (int j = 0; j < 4; ++j) {
      bool wrap = (v + (unsigned)j) >= 65u;
      unsigned off = (wrap ? offB : offA) + (unsigned)j;
      float2 p = sTab[off];
      float rr = wrap ? r2 : r;
      float oo = wrap ? omr2 : omr;
      o[j] = rr * p.y + oo * p.x;
    }
    *(f32x4*)(ob + base) = o;  // cached store: fill-anchored (zero-read loop)
  }
}

extern "C" void kernel_launch(void* const* d_in, const int* in_sizes, int n_in,
                              void* d_out, int out_size, void* d_ws, size_t ws_size,
                              hipStream_t stream) {
  const int* x = (const int*)d_in[0];
  const float* embed = (const float*)d_in[1];
  const float* hinit = (const float*)d_in[2];
  const float* thr = (const float*)d_in[3];
  const float* temp = (const float*)d_in[4];
  const float* ct = (const float*)d_in[5];
  const float* rt = (const float*)d_in[6];
  const float* outw = (const float*)d_in[7];
  float* ws = (float*)d_ws;
  float* out = (float*)d_out;

  hipLaunchKernelGGL(k_build, dim3(1), dim3(256), 0, stream, embed, ct, rt, hinit, outw, ws);
  // 512 blocks x (4 rows x 32 chunks) covers all 2048x32 (row,chunk) pairs
  hipLaunchKernelGGL(k_fused, dim3(512), dim3(256), 0, stream, x, ws, thr, temp, hinit, out);
}